// Round 3
// baseline (552.564 us; speedup 1.0000x reference)
//
#include <hip/hip_runtime.h>

// B=4096 rows, N=16384 cols, fp32.
// out = where(outlier(x - roll(x,1,axis=1)), 0, nan_to_zero(x))
// lower/upper = mean_grad -/+ 4*sqrt(var_grad), per column.
//
// Layout: 16 elems/thread (4 x float4), 256 thr/block -> 4096 cols/block,
// exactly 4 blocks per row (no row crossing inside a block).
// Circular-prev: in-thread chain; elem 0 comes from neighbor thread via LDS;
// thread 0 of each block does the single boundary load (wraps at col 0).

#define N_COLS 16384
#define EPT 16                      // elements per thread
#define BLOCK 256
#define COLS_PER_BLOCK (BLOCK * EPT)        // 4096
#define SEG_SHIFT 2                          // 4 blocks per row
#define SEG_MASK 3

typedef float f32x4 __attribute__((ext_vector_type(4)));  // native vec for nontemporal builtins

__device__ __forceinline__ float nan_clean(float v) {
    unsigned u = __float_as_uint(v);
    return ((u & 0x7f800000u) == 0x7f800000u) ? 0.0f : v;  // NaN/Inf -> 0
}

__global__ __launch_bounds__(BLOCK) void correction_kernel(
    const float* __restrict__ x,
    const float* __restrict__ mean_grad,
    const float* __restrict__ var_grad,
    float* __restrict__ out)
{
    const int tid = threadIdx.x;
    const int row = blockIdx.x >> SEG_SHIFT;
    const int seg = blockIdx.x & SEG_MASK;
    const int j0  = seg * COLS_PER_BLOCK + tid * EPT;   // starting column
    const long base = (long)row * N_COLS + j0;

    // ---- issue all global loads up front (64B payload + 128B bounds) ----
    const f32x4* xp = (const f32x4*)(x + base);
    f32x4 a0 = __builtin_nontemporal_load(xp + 0);
    f32x4 a1 = __builtin_nontemporal_load(xp + 1);
    f32x4 a2 = __builtin_nontemporal_load(xp + 2);
    f32x4 a3 = __builtin_nontemporal_load(xp + 3);

    const f32x4* mp = (const f32x4*)(mean_grad + j0);
    const f32x4* vp = (const f32x4*)(var_grad + j0);
    f32x4 m0 = mp[0], m1 = mp[1], m2 = mp[2], m3 = mp[3];
    f32x4 v0 = vp[0], v1 = vp[1], v2 = vp[2], v3 = vp[3];

    // boundary element for thread 0 (circular within the row)
    float boundary = 0.0f;
    if (tid == 0) {
        int jp = (j0 - 1 + N_COLS) & (N_COLS - 1);
        boundary = x[(long)row * N_COLS + jp];
    }

    // ---- clean ----
    float c[EPT];
    c[0]=nan_clean(a0.x);  c[1]=nan_clean(a0.y);  c[2]=nan_clean(a0.z);  c[3]=nan_clean(a0.w);
    c[4]=nan_clean(a1.x);  c[5]=nan_clean(a1.y);  c[6]=nan_clean(a1.z);  c[7]=nan_clean(a1.w);
    c[8]=nan_clean(a2.x);  c[9]=nan_clean(a2.y);  c[10]=nan_clean(a2.z); c[11]=nan_clean(a2.w);
    c[12]=nan_clean(a3.x); c[13]=nan_clean(a3.y); c[14]=nan_clean(a3.z); c[15]=nan_clean(a3.w);

    // ---- neighbor exchange of last element via LDS ----
    __shared__ float lastv[BLOCK];
    lastv[tid] = c[EPT - 1];
    __syncthreads();
    float prev = (tid == 0) ? nan_clean(boundary) : lastv[tid - 1];

    // ---- bounds + mask ----
    float m[EPT] = {m0.x,m0.y,m0.z,m0.w, m1.x,m1.y,m1.z,m1.w,
                    m2.x,m2.y,m2.z,m2.w, m3.x,m3.y,m3.z,m3.w};
    float vv[EPT] = {v0.x,v0.y,v0.z,v0.w, v1.x,v1.y,v1.z,v1.w,
                     v2.x,v2.y,v2.z,v2.w, v3.x,v3.y,v3.z,v3.w};

    float o[EPT];
    float pc = prev;
#pragma unroll
    for (int k = 0; k < EPT; ++k) {
        float d = c[k] - pc;
        float s = 4.0f * sqrtf(vv[k]);
        float lo = m[k] - s;
        float hi = m[k] + s;
        o[k] = (d < lo || d > hi) ? 0.0f : c[k];
        pc = c[k];
    }

    // ---- nontemporal stores (touch-once output) ----
    f32x4* op = (f32x4*)(out + base);
    f32x4 w0 = {o[0],o[1],o[2],o[3]};
    f32x4 w1 = {o[4],o[5],o[6],o[7]};
    f32x4 w2 = {o[8],o[9],o[10],o[11]};
    f32x4 w3 = {o[12],o[13],o[14],o[15]};
    __builtin_nontemporal_store(w0, op + 0);
    __builtin_nontemporal_store(w1, op + 1);
    __builtin_nontemporal_store(w2, op + 2);
    __builtin_nontemporal_store(w3, op + 3);
}

extern "C" void kernel_launch(void* const* d_in, const int* in_sizes, int n_in,
                              void* d_out, int out_size, void* d_ws, size_t ws_size,
                              hipStream_t stream) {
    const float* x  = (const float*)d_in[0];   // output   [B, N]
    const float* mg = (const float*)d_in[1];   // mean_grad [N]
    const float* vg = (const float*)d_in[2];   // var_grad  [N]
    float* out = (float*)d_out;

    int B = in_sizes[0] / N_COLS;                       // 4096
    int blocks_per_row = N_COLS / COLS_PER_BLOCK;       // 4
    int grid = B * blocks_per_row;                      // 16384

    correction_kernel<<<grid, BLOCK, 0, stream>>>(x, mg, vg, out);
}